// Round 4
// baseline (388.144 us; speedup 1.0000x reference)
//
#include <hip/hip_runtime.h>
#include <hip/hip_bf16.h>

typedef __hip_bfloat16 bf16;
typedef float f32x4 __attribute__((ext_vector_type(4)));
typedef short bf16x8 __attribute__((ext_vector_type(8)));
typedef short s16x4 __attribute__((ext_vector_type(4)));

#define NB 32
#define NC 256
#define NHID 128
#define NQKV 384
#define SMSCALE 0.17677669529663687f  // 32^-0.5
#define PADA 264                      // shorts per LDS A-row (256 + 8 pad)

// fp32 -> bf16 round-to-nearest-even (finite inputs)
__device__ __forceinline__ short f2bf(float f) {
  union { float f; unsigned u; } v;
  v.f = f;
  return (short)((v.u + 0x7fffu + ((v.u >> 16) & 1u)) >> 16);
}
__device__ __forceinline__ float bf2f(short s) {
  union { unsigned u; float f; } v;
  v.u = ((unsigned)(unsigned short)s) << 16;
  return v.f;
}

// ---------------- K0: weight prep -> FRAGMENT-READY bf16 layouts ----------------
// wqt: frag index (((s*8+ks)*6+nj)*64+lane)*8+e ; n = s*96+nj*16+(lane&15), k = ks*32+(lane>>4)*8+e
// wot: frag index (((w*4+ks)*4+nj)*64+lane)*8+e ; c = w*64+nj*16+(lane&15), k = ks*32+(lane>>4)*8+e
__global__ __launch_bounds__(256) void k_prep_w(const float* __restrict__ wqkv,
                                                const float* __restrict__ wout,
                                                short* __restrict__ wqt,
                                                short* __restrict__ wot) {
  int i = blockIdx.x * 256 + threadIdx.x;
  if (i < 98304) {
    int e = i & 7, l = (i >> 3) & 63, f = i >> 9;   // f = (s*8+ks)*6+nj
    int nj = f % 6, g = f / 6;
    int ks = g & 7, s = g >> 3;
    int n = s * 96 + nj * 16 + (l & 15);
    int k = ks * 32 + (l >> 4) * 8 + e;
    wqt[i] = f2bf(wqkv[(size_t)k * NQKV + n]);
  }
  if (i < 32768) {
    int e = i & 7, l = (i >> 3) & 63, f = i >> 9;   // f = (w*4+ks)*4+nj
    int nj = f & 3, g = f >> 2;
    int ks = g & 3, w = g >> 2;
    int c = w * 64 + nj * 16 + (l & 15);
    int k = ks * 32 + (l >> 4) * 8 + e;
    wot[i] = f2bf(wout[(size_t)k * NC + c]);
  }
}

// ---------------- K1: qkv = x @ w_qkv via MFMA, LDS-staged A, fused k-softmax, bf16 out ----------------
// __launch_bounds__(512,6): cap ~85 VGPR so 3 blocks (24 waves) fit per CU (was 2)
__global__ __launch_bounds__(512, 6) void k_gemm_qkv(const float* __restrict__ x,
                                                     const short* __restrict__ wqt,
                                                     short* __restrict__ qt,
                                                     short* __restrict__ kt,
                                                     short* __restrict__ vt) {
  __shared__ short As[64 * PADA];     // 33792 B; reused as Ks f32[64][132] after K-loop
  float* Ks = (float*)As;

  const int t = threadIdx.x;
  const int lane = t & 63;
  const int w = t >> 6;               // 0..7
  const int l15 = lane & 15;
  const int q = lane >> 4;            // 0..3
  const int h = w >> 2;               // m-half
  const int strip = (w & 3) * 96;
  const int rowBase = blockIdx.x * 64;
  const int b = rowBase >> 12;
  const int d = (rowBase >> 6) & 63;

  // stage x -> bf16 into LDS
  {
    const int r = w;
    const int c = (t & 63) * 4;
#pragma unroll
    for (int it = 0; it < 8; ++it) {
      int row = it * 8 + r;
      float4 f = *(const float4*)(x + (size_t)(rowBase + row) * NC + c);
      s16x4 sv;
      sv[0] = f2bf(f.x); sv[1] = f2bf(f.y); sv[2] = f2bf(f.z); sv[3] = f2bf(f.w);
      *(s16x4*)(As + row * PADA + c) = sv;
    }
  }
  __syncthreads();

  // fragment-ready B base for this wave's strip: fully-coalesced 1KB wave-loads
  const short* wqb = wqt + (((size_t)(w & 3) * 8) * 6) * 512 + lane * 8;

  f32x4 acc[2][6] = {};
  for (int ks = 0; ks < 8; ++ks) {
    const int k0 = ks * 32 + q * 8;
    bf16x8 afr[2];
#pragma unroll
    for (int mi = 0; mi < 2; ++mi)
      afr[mi] = *(const bf16x8*)(As + (h * 32 + mi * 16 + l15) * PADA + k0);
#pragma unroll
    for (int nj = 0; nj < 6; ++nj) {
      bf16x8 bfr = *(const bf16x8*)(wqb + (ks * 6 + nj) * 512);
#pragma unroll
      for (int mi = 0; mi < 2; ++mi)
        acc[mi][nj] = __builtin_amdgcn_mfma_f32_16x16x32_bf16(afr[mi], bfr, acc[mi][nj], 0, 0, 0);
    }
  }
  __syncthreads();  // all As reads complete before Ks overwrite

  // epilogue: q,v -> global bf16; k -> LDS fp32 for fused softmax
#pragma unroll
  for (int mi = 0; mi < 2; ++mi) {
#pragma unroll
    for (int nj = 0; nj < 6; ++nj) {
      const int g = strip + nj * 16 + l15;
      const int n_sp = h * 32 + mi * 16 + q * 4;
      if (g < 128) {
        s16x4 sv;
        sv[0] = f2bf(acc[mi][nj][0]); sv[1] = f2bf(acc[mi][nj][1]);
        sv[2] = f2bf(acc[mi][nj][2]); sv[3] = f2bf(acc[mi][nj][3]);
        *(s16x4*)(qt + (((size_t)(b * 128 + g)) << 12) + (d << 6) + n_sp) = sv;
      } else if (g < 256) {
        const int kc = g - 128;
#pragma unroll
        for (int rg = 0; rg < 4; ++rg)
          Ks[(n_sp + rg) * 132 + kc] = acc[mi][nj][rg];
      } else {
        s16x4 sv;
        sv[0] = f2bf(acc[mi][nj][0]); sv[1] = f2bf(acc[mi][nj][1]);
        sv[2] = f2bf(acc[mi][nj][2]); sv[3] = f2bf(acc[mi][nj][3]);
        *(s16x4*)(vt + (((size_t)(b * 128 + (g - 256))) << 12) + (d << 6) + n_sp) = sv;
      }
    }
  }
  __syncthreads();

  // fused k-softmax over the 128-channel axis, one row per 8-lane group
  {
    const int r = t >> 3;
    const int c0 = (t & 7) * 16;
    float vals[16];
    float m = -1e30f;
#pragma unroll
    for (int i = 0; i < 16; ++i) {
      vals[i] = Ks[r * 132 + c0 + i];
      m = fmaxf(m, vals[i]);
    }
    m = fmaxf(m, __shfl_xor(m, 1, 64));
    m = fmaxf(m, __shfl_xor(m, 2, 64));
    m = fmaxf(m, __shfl_xor(m, 4, 64));
    float s = 0.f;
#pragma unroll
    for (int i = 0; i < 16; ++i) {
      vals[i] = __expf(vals[i] - m);
      s += vals[i];
    }
    s += __shfl_xor(s, 1, 64);
    s += __shfl_xor(s, 2, 64);
    s += __shfl_xor(s, 4, 64);
    const float rinv = 1.f / s;
#pragma unroll
    for (int i = 0; i < 16; ++i)
      Ks[r * 132 + c0 + i] = vals[i] * rinv;
  }
  __syncthreads();

  // coalesced copy-out of normalized k as bf16
  {
    const int n = t & 63;
    const int c0 = (t >> 6) * 16;
    const size_t obase = (((size_t)(b * 128)) << 12) + (d << 6) + n;
#pragma unroll
    for (int i = 0; i < 16; ++i)
      kt[obase + (((size_t)(c0 + i)) << 12)] = f2bf(Ks[n * 132 + c0 + i]);
  }
}

// ---------------- K3: wave-per-channel attention, barrier-free ----------------
// block: 256 thr = 4 waves; wave w handles (b, ch = blockIdx.x*4+w) independently.
// K,V MFMA fragments loaded directly from global; P^T, ctx^T round-trip per-wave swizzled LDS.
__global__ __launch_bounds__(256) void k_attn(const short* __restrict__ kt,
                                              const short* __restrict__ vt,
                                              const short* __restrict__ qt,
                                              short* __restrict__ at) {
  __shared__ short SP[4][4096];  // per-wave P^T[n][d] (q-softmax'd, *scale), XOR-swizzled
  __shared__ short SC[4][4096];  // per-wave ctx^T[e][d], XOR-swizzled
  const int t = threadIdx.x;
  const int lane = t & 63;
  const int w = t >> 6;
  const int l15 = lane & 15;
  const int q = lane >> 4;
  const int ch = blockIdx.x * 4 + w;
  const int b = blockIdx.y;
  const size_t base = ((size_t)(b * 128 + ch)) << 12;
  short* sp = SP[w];
  short* sc = SC[w];

  // ---- q softmax over n: lane owns row d=lane (64 values in-register, no shuffles)
  {
    const short* qp = qt + base + lane * 64;
    bf16x8 qr[8];
#pragma unroll
    for (int u = 0; u < 8; ++u) qr[u] = *(const bf16x8*)(qp + u * 8);
    float vals[64];
    float m = -1e30f;
#pragma unroll
    for (int u = 0; u < 8; ++u)
#pragma unroll
      for (int i = 0; i < 8; ++i) {
        float f = bf2f(qr[u][i]);
        vals[u * 8 + i] = f;
        m = fmaxf(m, f);
      }
    float s = 0.f;
#pragma unroll
    for (int i = 0; i < 64; ++i) {
      vals[i] = __expf(vals[i] - m);
      s += vals[i];
    }
    const float r = SMSCALE / s;
    const int du = lane >> 3, dof = lane & 7;
#pragma unroll
    for (int n = 0; n < 64; ++n)
      sp[n * 64 + ((du ^ (n & 7)) << 3) + dof] = f2bf(vals[n] * r);
  }

  // ---- GEMM1: ctx[d][e] = sum_n K[d][n] V[e][n]; frags straight from global
  f32x4 acc1[4][4] = {};  // [ds][es]
#pragma unroll
  for (int ks = 0; ks < 2; ++ks) {
    bf16x8 kfr[4], vfr[4];
#pragma unroll
    for (int i = 0; i < 4; ++i) {
      kfr[i] = *(const bf16x8*)(kt + base + (i * 16 + l15) * 64 + ks * 32 + q * 8);
      vfr[i] = *(const bf16x8*)(vt + base + (i * 16 + l15) * 64 + ks * 32 + q * 8);
    }
#pragma unroll
    for (int ds = 0; ds < 4; ++ds)
#pragma unroll
      for (int es = 0; es < 4; ++es)
        acc1[ds][es] = __builtin_amdgcn_mfma_f32_16x16x32_bf16(kfr[ds], vfr[es], acc1[ds][es], 0, 0, 0);
  }
  // write ctx^T[e][d] to sc (swizzled): lane col e, rows d = ds*16+q*4+rg
#pragma unroll
  for (int ds = 0; ds < 4; ++ds)
#pragma unroll
    for (int es = 0; es < 4; ++es) {
      const int e = es * 16 + l15;
      const int d0 = ds * 16 + q * 4;
      s16x4 sv;
      sv[0] = f2bf(acc1[ds][es][0]); sv[1] = f2bf(acc1[ds][es][1]);
      sv[2] = f2bf(acc1[ds][es][2]); sv[3] = f2bf(acc1[ds][es][3]);
      *(s16x4*)(sc + e * 64 + (((d0 >> 3) ^ (e & 7)) << 3) + (d0 & 7)) = sv;
    }

  // ---- GEMM2: D[n][e] = sum_d P^T[n][d] ctx[d][e]  (wave-internal LDS deps, no barrier)
  f32x4 acc2[4][4] = {};  // [na][eb]
#pragma unroll
  for (int ks = 0; ks < 2; ++ks) {
    bf16x8 pfr[4], cfr[4];
#pragma unroll
    for (int i = 0; i < 4; ++i) {
      const int rn = i * 16 + l15;
      const int u = ((ks * 4 + q) ^ (rn & 7)) << 3;
      pfr[i] = *(const bf16x8*)(sp + rn * 64 + u);
      cfr[i] = *(const bf16x8*)(sc + rn * 64 + u);
    }
#pragma unroll
    for (int na = 0; na < 4; ++na)
#pragma unroll
      for (int eb = 0; eb < 4; ++eb)
        acc2[na][eb] = __builtin_amdgcn_mfma_f32_16x16x32_bf16(pfr[na], cfr[eb], acc2[na][eb], 0, 0, 0);
  }
  // store at[e][n]: lane col e, rows n = na*16+q*4+rg (4 consecutive n -> s16x4)
#pragma unroll
  for (int na = 0; na < 4; ++na)
#pragma unroll
    for (int eb = 0; eb < 4; ++eb) {
      const int e = eb * 16 + l15;
      const int n0 = na * 16 + q * 4;
      s16x4 sv;
      sv[0] = f2bf(acc2[na][eb][0]); sv[1] = f2bf(acc2[na][eb][1]);
      sv[2] = f2bf(acc2[na][eb][2]); sv[3] = f2bf(acc2[na][eb][3]);
      *(s16x4*)(at + base + e * 64 + n0) = sv;
    }
}

// ---------------- K4: yb = attn @ w_out + b_out (bf16 out via LDS repack) + GN partial sums ----------------
__global__ __launch_bounds__(256) void k_gemm_out(const short* __restrict__ at,
                                                  const short* __restrict__ wot,
                                                  const float* __restrict__ bias,
                                                  short* __restrict__ yb,
                                                  float* __restrict__ sums) {
  __shared__ short As[8448];  // K-loop: [m][128] swizzled (stride 128); epilogue: Ys [32][264]
  __shared__ float red[8];
  const int t = threadIdx.x;
  const int lane = t & 63;
  const int w = t >> 6;
  const int l15 = lane & 15;
  const int q = lane >> 4;
  const int rowBase = blockIdx.x * 64;
  const int b = rowBase >> 12;
  const int r0 = rowBase & 4095;
  const size_t abase = (((size_t)(b * 128)) << 12) + r0;
  // stage at[ch][r] (bf16) -> As[r][ch] via 4x4 in-register transpose
  {
    const int tr = t & 15;
    const int tk = t >> 4;
#pragma unroll
    for (int i = 0; i < 2; ++i) {
      const int kq = tk + 16 * i;
      s16x4 f[4];
#pragma unroll
      for (int kc = 0; kc < 4; ++kc)
        f[kc] = *(const s16x4*)(at + abase + (((size_t)(kq * 4 + kc)) << 12) + tr * 4);
      const int ul = kq >> 1, hh = kq & 1;
#pragma unroll
      for (int j = 0; j < 4; ++j) {
        int m = tr * 4 + j;
        s16x4 sv;
        sv[0] = f[0][j]; sv[1] = f[1][j]; sv[2] = f[2][j]; sv[3] = f[3][j];
        *(s16x4*)(As + m * 128 + ((ul ^ (m & 15)) << 3) + hh * 4) = sv;
      }
    }
  }
  __syncthreads();
  const short* wob = wot + ((size_t)(w * 4) * 4) * 512 + lane * 8;
  f32x4 acc[4][4] = {};
  for (int ks = 0; ks < 4; ++ks) {
    bf16x8 afr[4];
#pragma unroll
    for (int mi = 0; mi < 4; ++mi) {
      int m = mi * 16 + l15;
      int ul = ks * 4 + q;
      afr[mi] = *(const bf16x8*)(As + m * 128 + ((ul ^ (m & 15)) << 3));
    }
#pragma unroll
    for (int nj = 0; nj < 4; ++nj) {
      bf16x8 bfr = *(const bf16x8*)(wob + (ks * 4 + nj) * 512);
#pragma unroll
      for (int mi = 0; mi < 4; ++mi)
        acc[mi][nj] = __builtin_amdgcn_mfma_f32_16x16x32_bf16(afr[mi], bfr, acc[mi][nj], 0, 0, 0);
    }
  }
  // epilogue: bias + GN sums; route y through LDS (two 32-row halves) for coalesced bf16 stores
  float ls = 0.f, lss = 0.f;
#pragma unroll
  for (int hh = 0; hh < 2; ++hh) {
    __syncthreads();  // As reads (K-loop / prev copy-out) done before overwrite
#pragma unroll
    for (int mi2 = 0; mi2 < 2; ++mi2) {
      const int mi = hh * 2 + mi2;
#pragma unroll
      for (int nj = 0; nj < 4; ++nj) {
        const int c = w * 64 + nj * 16 + l15;
        const float bv = bias[c];
#pragma unroll
        for (int rg = 0; rg < 4; ++rg) {
          float v = acc[mi][nj][rg] + bv;
          ls += v;
          lss += v * v;
          As[(mi2 * 16 + q * 4 + rg) * 264 + c] = f2bf(v);
        }
      }
    }
    __syncthreads();
    {
      const int r = t >> 3;            // 0..31
      const int c0 = (t & 7) * 32;     // 0..224
      const size_t orow = (size_t)(rowBase + hh * 32 + r) * NC + c0;
#pragma unroll
      for (int u = 0; u < 4; ++u)
        *(bf16x8*)(yb + orow + u * 8) = *(const bf16x8*)(As + r * 264 + c0 + u * 8);
    }
  }
#pragma unroll
  for (int off = 32; off; off >>= 1) {
    ls += __shfl_xor(ls, off, 64);
    lss += __shfl_xor(lss, off, 64);
  }
  if (lane == 0) {
    red[w] = ls;
    red[4 + w] = lss;
  }
  __syncthreads();
  if (t == 0) {
    float S = red[0] + red[1] + red[2] + red[3];
    float SS = red[4] + red[5] + red[6] + red[7];
    atomicAdd(&sums[2 * b], S);
    atomicAdd(&sums[2 * b + 1], SS);
  }
}

// ---------------- K5: GroupNorm(1 group) finalize: bf16 in, fp32 out ----------------
__global__ __launch_bounds__(256) void k_gnorm(const short* __restrict__ yb,
                                               float* __restrict__ out,
                                               const float* __restrict__ sums,
                                               const float* __restrict__ gs,
                                               const float* __restrict__ gb) {
  size_t i0 = ((size_t)blockIdx.x * 256 + threadIdx.x) * 8;
  int b = (int)(i0 >> 20);
  int c = (int)(i0 & 255);
  const float invN = 1.0f / 1048576.0f;
  float mean = sums[2 * b] * invN;
  float var = sums[2 * b + 1] * invN - mean * mean;
  float inv = rsqrtf(var + 1e-6f);
  bf16x8 v = *(const bf16x8*)(yb + i0);
  float4 g0 = *(const float4*)(gs + c);
  float4 g1 = *(const float4*)(gs + c + 4);
  float4 b0 = *(const float4*)(gb + c);
  float4 b1 = *(const float4*)(gb + c + 4);
  float4 r0, r1;
  r0.x = (bf2f(v[0]) - mean) * inv * g0.x + b0.x;
  r0.y = (bf2f(v[1]) - mean) * inv * g0.y + b0.y;
  r0.z = (bf2f(v[2]) - mean) * inv * g0.z + b0.z;
  r0.w = (bf2f(v[3]) - mean) * inv * g0.w + b0.w;
  r1.x = (bf2f(v[4]) - mean) * inv * g1.x + b1.x;
  r1.y = (bf2f(v[5]) - mean) * inv * g1.y + b1.y;
  r1.z = (bf2f(v[6]) - mean) * inv * g1.z + b1.z;
  r1.w = (bf2f(v[7]) - mean) * inv * g1.w + b1.w;
  *((float4*)(out + i0)) = r0;
  *((float4*)(out + i0 + 4)) = r1;
}

extern "C" void kernel_launch(void* const* d_in, const int* in_sizes, int n_in,
                              void* d_out, int out_size, void* d_ws, size_t ws_size,
                              hipStream_t stream) {
  const float* x = (const float*)d_in[0];
  const float* w_qkv = (const float*)d_in[1];
  const float* w_out = (const float*)d_in[2];
  const float* b_out = (const float*)d_in[3];
  const float* gn_scale = (const float*)d_in[4];
  const float* gn_bias = (const float*)d_in[5];
  float* out = (float*)d_out;

  char* ws = (char*)d_ws;
  const size_t SLAB = (size_t)67108864;  // 64 MiB
  short* qt = (short*)ws;
  short* kt = (short*)(ws + SLAB);
  short* vt = (short*)(ws + 2 * SLAB);
  short* at = qt;   // alias: k_attn consumes its qt slice before writing its at slice
  short* yb = kt;   // alias: kt fully consumed by k_attn before k_gemm_out writes yb
  float* sums = (float*)(ws + 3 * SLAB);
  short* wqt = (short*)(ws + 3 * SLAB + 1024);
  short* wot = (short*)(ws + 3 * SLAB + 1024 + 196608);

  hipMemsetAsync(sums, 0, 64 * sizeof(float), stream);

  k_prep_w<<<384, 256, 0, stream>>>(w_qkv, w_out, wqt, wot);
  k_gemm_qkv<<<2048, 512, 0, stream>>>(x, wqt, qt, kt, vt);
  k_attn<<<dim3(32, 32), 256, 0, stream>>>(kt, vt, qt, at);
  k_gemm_out<<<2048, 256, 0, stream>>>(at, wot, b_out, yb, sums);
  k_gnorm<<<16384, 256, 0, stream>>>(yb, out, sums, gn_scale, gn_bias);
}

// Round 5
// 373.801 us; speedup vs baseline: 1.0384x; 1.0384x over previous
//
#include <hip/hip_runtime.h>
#include <hip/hip_bf16.h>

typedef __hip_bfloat16 bf16;
typedef float f32x4 __attribute__((ext_vector_type(4)));
typedef short bf16x8 __attribute__((ext_vector_type(8)));
typedef short s16x4 __attribute__((ext_vector_type(4)));

#define NB 32
#define NC 256
#define NHID 128
#define NQKV 384
#define SMSCALE 0.17677669529663687f  // 32^-0.5
#define PADA 264                      // shorts per LDS A-row (256 + 8 pad)
#define PADQ 72                       // shorts per QL/VL row (64 + 8; 144B keeps 16B align)

// fp32 -> bf16 round-to-nearest-even (finite inputs)
__device__ __forceinline__ short f2bf(float f) {
  union { float f; unsigned u; } v;
  v.f = f;
  return (short)((v.u + 0x7fffu + ((v.u >> 16) & 1u)) >> 16);
}
__device__ __forceinline__ float bf2f(short s) {
  union { unsigned u; float f; } v;
  v.u = ((unsigned)(unsigned short)s) << 16;
  return v.f;
}

// ---------------- K0: weight prep -> FRAGMENT-READY bf16 layouts ----------------
// wqt: frag index (((s*8+ks)*6+nj)*64+lane)*8+e ; n = s*96+nj*16+(lane&15), k = ks*32+(lane>>4)*8+e
// wot: frag index (((w*4+ks)*4+nj)*64+lane)*8+e ; c = w*64+nj*16+(lane&15), k = ks*32+(lane>>4)*8+e
__global__ __launch_bounds__(256) void k_prep_w(const float* __restrict__ wqkv,
                                                const float* __restrict__ wout,
                                                short* __restrict__ wqt,
                                                short* __restrict__ wot) {
  int i = blockIdx.x * 256 + threadIdx.x;
  if (i < 98304) {
    int e = i & 7, l = (i >> 3) & 63, f = i >> 9;   // f = (s*8+ks)*6+nj
    int nj = f % 6, g = f / 6;
    int ks = g & 7, s = g >> 3;
    int n = s * 96 + nj * 16 + (l & 15);
    int k = ks * 32 + (l >> 4) * 8 + e;
    wqt[i] = f2bf(wqkv[(size_t)k * NQKV + n]);
  }
  if (i < 32768) {
    int e = i & 7, l = (i >> 3) & 63, f = i >> 9;   // f = (w*4+ks)*4+nj
    int nj = f & 3, g = f >> 2;
    int ks = g & 3, w = g >> 2;
    int c = w * 64 + nj * 16 + (l & 15);
    int k = ks * 32 + (l >> 4) * 8 + e;
    wot[i] = f2bf(wout[(size_t)k * NC + c]);
  }
}

// ---------------- K1: qkv = x @ w_qkv via MFMA; LDS-staged A; ALL outputs LDS-repacked ----------------
// plain launch_bounds(512): R4's (512,6) cap caused scratch spills (WRITE_SIZE +10MB)
__global__ __launch_bounds__(512) void k_gemm_qkv(const float* __restrict__ x,
                                                  const short* __restrict__ wqt,
                                                  short* __restrict__ qt,
                                                  short* __restrict__ kt,
                                                  short* __restrict__ vt) {
  __shared__ short As[64 * PADA];     // 33792 B; reused as Ks f32[64][132] after K-loop
  __shared__ short QL[128 * PADQ];    // 18432 B: q epilogue repack [ch][n]
  __shared__ short VL[128 * PADQ];    // 18432 B: v epilogue repack [ch][n]
  float* Ks = (float*)As;

  const int t = threadIdx.x;
  const int lane = t & 63;
  const int w = t >> 6;               // 0..7
  const int l15 = lane & 15;
  const int q = lane >> 4;            // 0..3
  const int h = w >> 2;               // m-half
  const int strip = (w & 3) * 96;
  const int rowBase = blockIdx.x * 64;
  const int b = rowBase >> 12;
  const int d = (rowBase >> 6) & 63;

  // stage x -> bf16 into LDS
  {
    const int r = w;
    const int c = (t & 63) * 4;
#pragma unroll
    for (int it = 0; it < 8; ++it) {
      int row = it * 8 + r;
      float4 f = *(const float4*)(x + (size_t)(rowBase + row) * NC + c);
      s16x4 sv;
      sv[0] = f2bf(f.x); sv[1] = f2bf(f.y); sv[2] = f2bf(f.z); sv[3] = f2bf(f.w);
      *(s16x4*)(As + row * PADA + c) = sv;
    }
  }
  __syncthreads();

  // fragment-ready B base for this wave's strip: fully-coalesced 1KB wave-loads
  const short* wqb = wqt + (((size_t)(w & 3) * 8) * 6) * 512 + lane * 8;

  f32x4 acc[2][6] = {};
  for (int ks = 0; ks < 8; ++ks) {
    const int k0 = ks * 32 + q * 8;
    bf16x8 afr[2];
#pragma unroll
    for (int mi = 0; mi < 2; ++mi)
      afr[mi] = *(const bf16x8*)(As + (h * 32 + mi * 16 + l15) * PADA + k0);
#pragma unroll
    for (int nj = 0; nj < 6; ++nj) {
      bf16x8 bfr = *(const bf16x8*)(wqb + (ks * 6 + nj) * 512);
#pragma unroll
      for (int mi = 0; mi < 2; ++mi)
        acc[mi][nj] = __builtin_amdgcn_mfma_f32_16x16x32_bf16(afr[mi], bfr, acc[mi][nj], 0, 0, 0);
    }
  }
  __syncthreads();  // all As reads complete before Ks overwrite

  // epilogue: q -> QL bf16, k -> Ks fp32, v -> VL bf16 (all LDS; no scattered global stores)
#pragma unroll
  for (int mi = 0; mi < 2; ++mi) {
#pragma unroll
    for (int nj = 0; nj < 6; ++nj) {
      const int g = strip + nj * 16 + l15;
      const int n_sp = h * 32 + mi * 16 + q * 4;
      if (g < 128) {
        s16x4 sv;
        sv[0] = f2bf(acc[mi][nj][0]); sv[1] = f2bf(acc[mi][nj][1]);
        sv[2] = f2bf(acc[mi][nj][2]); sv[3] = f2bf(acc[mi][nj][3]);
        *(s16x4*)(QL + g * PADQ + n_sp) = sv;
      } else if (g < 256) {
        const int kc = g - 128;
#pragma unroll
        for (int rg = 0; rg < 4; ++rg)
          Ks[(n_sp + rg) * 132 + kc] = acc[mi][nj][rg];
      } else {
        s16x4 sv;
        sv[0] = f2bf(acc[mi][nj][0]); sv[1] = f2bf(acc[mi][nj][1]);
        sv[2] = f2bf(acc[mi][nj][2]); sv[3] = f2bf(acc[mi][nj][3]);
        *(s16x4*)(VL + (g - 256) * PADQ + n_sp) = sv;
      }
    }
  }
  __syncthreads();

  // fused k-softmax over the 128-channel axis, one row per 8-lane group (in-place in Ks)
  {
    const int r = t >> 3;
    const int c0 = (t & 7) * 16;
    float vals[16];
    float m = -1e30f;
#pragma unroll
    for (int i = 0; i < 16; ++i) {
      vals[i] = Ks[r * 132 + c0 + i];
      m = fmaxf(m, vals[i]);
    }
    m = fmaxf(m, __shfl_xor(m, 1, 64));
    m = fmaxf(m, __shfl_xor(m, 2, 64));
    m = fmaxf(m, __shfl_xor(m, 4, 64));
    float s = 0.f;
#pragma unroll
    for (int i = 0; i < 16; ++i) {
      vals[i] = __expf(vals[i] - m);
      s += vals[i];
    }
    s += __shfl_xor(s, 1, 64);
    s += __shfl_xor(s, 2, 64);
    s += __shfl_xor(s, 4, 64);
    const float rinv = 1.f / s;
#pragma unroll
    for (int i = 0; i < 16; ++i)
      Ks[r * 132 + c0 + i] = vals[i] * rinv;
  }
  __syncthreads();

  // coalesced copy-outs: per channel row = 128B contiguous; 8 lanes cover it with 16B chunks
  {
    const int c = t & 7;            // 16B chunk within the 64-short channel row
    const int g0 = t >> 3;          // 0..63
#pragma unroll
    for (int p = 0; p < 2; ++p) {
      const int g = g0 + p * 64;
      const size_t obase = (((size_t)(b * 128 + g)) << 12) + (d << 6) + c * 8;
      bf16x8 qv = *(const bf16x8*)(QL + g * PADQ + c * 8);
      bf16x8 vv = *(const bf16x8*)(VL + g * PADQ + c * 8);
      *(bf16x8*)(qt + obase) = qv;
      *(bf16x8*)(vt + obase) = vv;
    }
  }
  // normalized k copy-out (lane-contiguous in n; 128B lines fully used)
  {
    const int n = t & 63;
    const int c0 = (t >> 6) * 16;
    const size_t obase = (((size_t)(b * 128)) << 12) + (d << 6) + n;
#pragma unroll
    for (int i = 0; i < 16; ++i)
      kt[obase + (((size_t)(c0 + i)) << 12)] = f2bf(Ks[n * 132 + c0 + i]);
  }
}

// ---------------- K3: wave-per-channel attention, barrier-free ----------------
// block: 256 thr = 4 waves; wave w handles (b, ch = blockIdx.x*4+w) independently.
// K,V MFMA fragments loaded directly from global; P^T, ctx^T round-trip per-wave swizzled LDS.
// D-tile repacked into sp (P dead after GEMM2) for fully-coalesced 16B stores.
__global__ __launch_bounds__(256) void k_attn(const short* __restrict__ kt,
                                              const short* __restrict__ vt,
                                              const short* __restrict__ qt,
                                              short* __restrict__ at) {
  __shared__ short SP[4][4096];  // per-wave P^T[n][d] (q-softmax'd, *scale), XOR-swizzled; then D[e][n]
  __shared__ short SC[4][4096];  // per-wave ctx^T[e][d], XOR-swizzled
  const int t = threadIdx.x;
  const int lane = t & 63;
  const int w = t >> 6;
  const int l15 = lane & 15;
  const int q = lane >> 4;
  const int ch = blockIdx.x * 4 + w;
  const int b = blockIdx.y;
  const size_t base = ((size_t)(b * 128 + ch)) << 12;
  short* sp = SP[w];
  short* sc = SC[w];

  // ---- q softmax over n: lane owns row d=lane (64 values in-register, no shuffles)
  {
    const short* qp = qt + base + lane * 64;
    bf16x8 qr[8];
#pragma unroll
    for (int u = 0; u < 8; ++u) qr[u] = *(const bf16x8*)(qp + u * 8);
    float vals[64];
    float m = -1e30f;
#pragma unroll
    for (int u = 0; u < 8; ++u)
#pragma unroll
      for (int i = 0; i < 8; ++i) {
        float f = bf2f(qr[u][i]);
        vals[u * 8 + i] = f;
        m = fmaxf(m, f);
      }
    float s = 0.f;
#pragma unroll
    for (int i = 0; i < 64; ++i) {
      vals[i] = __expf(vals[i] - m);
      s += vals[i];
    }
    const float r = SMSCALE / s;
    const int du = lane >> 3, dof = lane & 7;
#pragma unroll
    for (int n = 0; n < 64; ++n)
      sp[n * 64 + ((du ^ (n & 7)) << 3) + dof] = f2bf(vals[n] * r);
  }

  // ---- GEMM1: ctx[d][e] = sum_n K[d][n] V[e][n]; frags straight from global
  f32x4 acc1[4][4] = {};  // [ds][es]
#pragma unroll
  for (int ks = 0; ks < 2; ++ks) {
    bf16x8 kfr[4], vfr[4];
#pragma unroll
    for (int i = 0; i < 4; ++i) {
      kfr[i] = *(const bf16x8*)(kt + base + (i * 16 + l15) * 64 + ks * 32 + q * 8);
      vfr[i] = *(const bf16x8*)(vt + base + (i * 16 + l15) * 64 + ks * 32 + q * 8);
    }
#pragma unroll
    for (int ds = 0; ds < 4; ++ds)
#pragma unroll
      for (int es = 0; es < 4; ++es)
        acc1[ds][es] = __builtin_amdgcn_mfma_f32_16x16x32_bf16(kfr[ds], vfr[es], acc1[ds][es], 0, 0, 0);
  }
  // write ctx^T[e][d] to sc (swizzled): lane col e, rows d = ds*16+q*4+rg
#pragma unroll
  for (int ds = 0; ds < 4; ++ds)
#pragma unroll
    for (int es = 0; es < 4; ++es) {
      const int e = es * 16 + l15;
      const int d0 = ds * 16 + q * 4;
      s16x4 sv;
      sv[0] = f2bf(acc1[ds][es][0]); sv[1] = f2bf(acc1[ds][es][1]);
      sv[2] = f2bf(acc1[ds][es][2]); sv[3] = f2bf(acc1[ds][es][3]);
      *(s16x4*)(sc + e * 64 + (((d0 >> 3) ^ (e & 7)) << 3) + (d0 & 7)) = sv;
    }

  // ---- GEMM2: D[n][e] = sum_d P^T[n][d] ctx[d][e]  (wave-internal LDS deps, no barrier)
  f32x4 acc2[4][4] = {};  // [na][eb]
#pragma unroll
  for (int ks = 0; ks < 2; ++ks) {
    bf16x8 pfr[4], cfr[4];
#pragma unroll
    for (int i = 0; i < 4; ++i) {
      const int rn = i * 16 + l15;
      const int u = ((ks * 4 + q) ^ (rn & 7)) << 3;
      pfr[i] = *(const bf16x8*)(sp + rn * 64 + u);
      cfr[i] = *(const bf16x8*)(sc + rn * 64 + u);
    }
#pragma unroll
    for (int na = 0; na < 4; ++na)
#pragma unroll
      for (int eb = 0; eb < 4; ++eb)
        acc2[na][eb] = __builtin_amdgcn_mfma_f32_16x16x32_bf16(pfr[na], cfr[eb], acc2[na][eb], 0, 0, 0);
  }
  // repack D[e][n] into sp (P dead), 8B-unit XOR swizzle: phys_unit = (n>>2) ^ (e&15)
#pragma unroll
  for (int na = 0; na < 4; ++na)
#pragma unroll
    for (int eb = 0; eb < 4; ++eb) {
      const int e = eb * 16 + l15;
      const int n0 = na * 16 + q * 4;
      const int un = (((n0 >> 2) ^ (e & 15)) << 2);
      s16x4 sv;
      sv[0] = f2bf(acc2[na][eb][0]); sv[1] = f2bf(acc2[na][eb][1]);
      sv[2] = f2bf(acc2[na][eb][2]); sv[3] = f2bf(acc2[na][eb][3]);
      *(s16x4*)(sp + e * 64 + un) = sv;
    }
  // coalesced store: 8 e-rows x 128B fully-used lines per instruction
#pragma unroll
  for (int p = 0; p < 8; ++p) {
    const int e = p * 8 + (lane >> 3);
    const int c = lane & 7;  // 16B chunk = units 2c, 2c+1
    const int u0 = (((2 * c) ^ (e & 15)) << 2);
    const int u1 = (((2 * c + 1) ^ (e & 15)) << 2);
    s16x4 a = *(const s16x4*)(sp + e * 64 + u0);
    s16x4 bb = *(const s16x4*)(sp + e * 64 + u1);
    bf16x8 o8;
    o8[0] = a[0]; o8[1] = a[1]; o8[2] = a[2]; o8[3] = a[3];
    o8[4] = bb[0]; o8[5] = bb[1]; o8[6] = bb[2]; o8[7] = bb[3];
    *(bf16x8*)(at + base + e * 64 + c * 8) = o8;
  }
}

// ---------------- K4: yb = attn @ w_out + b_out (bf16 out via LDS repack) + GN partial sums ----------------
__global__ __launch_bounds__(256) void k_gemm_out(const short* __restrict__ at,
                                                  const short* __restrict__ wot,
                                                  const float* __restrict__ bias,
                                                  short* __restrict__ yb,
                                                  float* __restrict__ sums) {
  __shared__ short As[8448];  // K-loop: [m][128] swizzled (stride 128); epilogue: Ys [32][264]
  __shared__ float red[8];
  const int t = threadIdx.x;
  const int lane = t & 63;
  const int w = t >> 6;
  const int l15 = lane & 15;
  const int q = lane >> 4;
  const int rowBase = blockIdx.x * 64;
  const int b = rowBase >> 12;
  const int r0 = rowBase & 4095;
  const size_t abase = (((size_t)(b * 128)) << 12) + r0;
  // stage at[ch][r] (bf16) -> As[r][ch] via 4x4 in-register transpose
  {
    const int tr = t & 15;
    const int tk = t >> 4;
#pragma unroll
    for (int i = 0; i < 2; ++i) {
      const int kq = tk + 16 * i;
      s16x4 f[4];
#pragma unroll
      for (int kc = 0; kc < 4; ++kc)
        f[kc] = *(const s16x4*)(at + abase + (((size_t)(kq * 4 + kc)) << 12) + tr * 4);
      const int ul = kq >> 1, hh = kq & 1;
#pragma unroll
      for (int j = 0; j < 4; ++j) {
        int m = tr * 4 + j;
        s16x4 sv;
        sv[0] = f[0][j]; sv[1] = f[1][j]; sv[2] = f[2][j]; sv[3] = f[3][j];
        *(s16x4*)(As + m * 128 + ((ul ^ (m & 15)) << 3) + hh * 4) = sv;
      }
    }
  }
  __syncthreads();
  const short* wob = wot + ((size_t)(w * 4) * 4) * 512 + lane * 8;
  f32x4 acc[4][4] = {};
  for (int ks = 0; ks < 4; ++ks) {
    bf16x8 afr[4];
#pragma unroll
    for (int mi = 0; mi < 4; ++mi) {
      int m = mi * 16 + l15;
      int ul = ks * 4 + q;
      afr[mi] = *(const bf16x8*)(As + m * 128 + ((ul ^ (m & 15)) << 3));
    }
#pragma unroll
    for (int nj = 0; nj < 4; ++nj) {
      bf16x8 bfr = *(const bf16x8*)(wob + (ks * 4 + nj) * 512);
#pragma unroll
      for (int mi = 0; mi < 4; ++mi)
        acc[mi][nj] = __builtin_amdgcn_mfma_f32_16x16x32_bf16(afr[mi], bfr, acc[mi][nj], 0, 0, 0);
    }
  }
  // epilogue: bias + GN sums; route y through LDS (two 32-row halves) for coalesced bf16 stores
  float ls = 0.f, lss = 0.f;
#pragma unroll
  for (int hh = 0; hh < 2; ++hh) {
    __syncthreads();  // As reads (K-loop / prev copy-out) done before overwrite
#pragma unroll
    for (int mi2 = 0; mi2 < 2; ++mi2) {
      const int mi = hh * 2 + mi2;
#pragma unroll
      for (int nj = 0; nj < 4; ++nj) {
        const int c = w * 64 + nj * 16 + l15;
        const float bv = bias[c];
#pragma unroll
        for (int rg = 0; rg < 4; ++rg) {
          float v = acc[mi][nj][rg] + bv;
          ls += v;
          lss += v * v;
          As[(mi2 * 16 + q * 4 + rg) * 264 + c] = f2bf(v);
        }
      }
    }
    __syncthreads();
    {
      const int r = t >> 3;            // 0..31
      const int c0 = (t & 7) * 32;     // 0..224
      const size_t orow = (size_t)(rowBase + hh * 32 + r) * NC + c0;
#pragma unroll
      for (int u = 0; u < 4; ++u)
        *(bf16x8*)(yb + orow + u * 8) = *(const bf16x8*)(As + r * 264 + c0 + u * 8);
    }
  }
#pragma unroll
  for (int off = 32; off; off >>= 1) {
    ls += __shfl_xor(ls, off, 64);
    lss += __shfl_xor(lss, off, 64);
  }
  if (lane == 0) {
    red[w] = ls;
    red[4 + w] = lss;
  }
  __syncthreads();
  if (t == 0) {
    float S = red[0] + red[1] + red[2] + red[3];
    float SS = red[4] + red[5] + red[6] + red[7];
    atomicAdd(&sums[2 * b], S);
    atomicAdd(&sums[2 * b + 1], SS);
  }
}

// ---------------- K5: GroupNorm(1 group) finalize: bf16 in, fp32 out ----------------
__global__ __launch_bounds__(256) void k_gnorm(const short* __restrict__ yb,
                                               float* __restrict__ out,
                                               const float* __restrict__ sums,
                                               const float* __restrict__ gs,
                                               const float* __restrict__ gb) {
  size_t i0 = ((size_t)blockIdx.x * 256 + threadIdx.x) * 8;
  int b = (int)(i0 >> 20);
  int c = (int)(i0 & 255);
  const float invN = 1.0f / 1048576.0f;
  float mean = sums[2 * b] * invN;
  float var = sums[2 * b + 1] * invN - mean * mean;
  float inv = rsqrtf(var + 1e-6f);
  bf16x8 v = *(const bf16x8*)(yb + i0);
  float4 g0 = *(const float4*)(gs + c);
  float4 g1 = *(const float4*)(gs + c + 4);
  float4 b0 = *(const float4*)(gb + c);
  float4 b1 = *(const float4*)(gb + c + 4);
  float4 r0, r1;
  r0.x = (bf2f(v[0]) - mean) * inv * g0.x + b0.x;
  r0.y = (bf2f(v[1]) - mean) * inv * g0.y + b0.y;
  r0.z = (bf2f(v[2]) - mean) * inv * g0.z + b0.z;
  r0.w = (bf2f(v[3]) - mean) * inv * g0.w + b0.w;
  r1.x = (bf2f(v[4]) - mean) * inv * g1.x + b1.x;
  r1.y = (bf2f(v[5]) - mean) * inv * g1.y + b1.y;
  r1.z = (bf2f(v[6]) - mean) * inv * g1.z + b1.z;
  r1.w = (bf2f(v[7]) - mean) * inv * g1.w + b1.w;
  *((float4*)(out + i0)) = r0;
  *((float4*)(out + i0 + 4)) = r1;
}

extern "C" void kernel_launch(void* const* d_in, const int* in_sizes, int n_in,
                              void* d_out, int out_size, void* d_ws, size_t ws_size,
                              hipStream_t stream) {
  const float* x = (const float*)d_in[0];
  const float* w_qkv = (const float*)d_in[1];
  const float* w_out = (const float*)d_in[2];
  const float* b_out = (const float*)d_in[3];
  const float* gn_scale = (const float*)d_in[4];
  const float* gn_bias = (const float*)d_in[5];
  float* out = (float*)d_out;

  char* ws = (char*)d_ws;
  const size_t SLAB = (size_t)67108864;  // 64 MiB
  short* qt = (short*)ws;
  short* kt = (short*)(ws + SLAB);
  short* vt = (short*)(ws + 2 * SLAB);
  short* at = qt;   // alias: k_attn consumes its qt slice before writing its at slice
  short* yb = kt;   // alias: kt fully consumed by k_attn before k_gemm_out writes yb
  float* sums = (float*)(ws + 3 * SLAB);
  short* wqt = (short*)(ws + 3 * SLAB + 1024);
  short* wot = (short*)(ws + 3 * SLAB + 1024 + 196608);

  hipMemsetAsync(sums, 0, 64 * sizeof(float), stream);

  k_prep_w<<<384, 256, 0, stream>>>(w_qkv, w_out, wqt, wot);
  k_gemm_qkv<<<2048, 512, 0, stream>>>(x, wqt, qt, kt, vt);
  k_attn<<<dim3(32, 32), 256, 0, stream>>>(kt, vt, qt, at);
  k_gemm_out<<<2048, 256, 0, stream>>>(at, wot, b_out, yb, sums);
  k_gnorm<<<16384, 256, 0, stream>>>(yb, out, sums, gn_scale, gn_bias);
}